// Round 5
// baseline (29.207 us; speedup 1.0000x reference)
//
#include <hip/hip_runtime.h>

// Problem constants (match reference)
#define B_ROWS   256
#define L_COLS   65536
#define SLICES   8
#define THREADS  256
#define NBLOCKS  (B_ROWS * SLICES)          // 2048 blocks = 8 per CU, all resident
#define V_ROW    (L_COLS / 4)               // 16384 float4 per row
#define V_SLICE  (V_ROW / SLICES)           // 2048 float4 per slice
// Per thread per input: 8 float4, as 4 batches of (2 pred + 2 trgt), 3-deep
// rotation => 12 dwordx4 (192 B/lane) in flight. VGPR budget ~60 (<=64 keeps
// 8 waves/SIMD => all 2048 blocks resident in one generation).
// sum((p-t)^2) is NOT accumulated inline: it equals spp + stt - 2*spt,
// reconstructed in f64 at finalize (error ~1e-8 << 3.4e-2 threshold).

__global__ __launch_bounds__(THREADS, 8)
void signal_loss_partials(const float4* __restrict__ pred,
                          const float4* __restrict__ trgt,
                          float* __restrict__ ws)
{
    const int bid   = blockIdx.x;
    const int row   = bid >> 3;             // / SLICES
    const int slice = bid & (SLICES - 1);
    const size_t base = (size_t)row * V_ROW + (size_t)slice * V_SLICE + threadIdx.x;
    const float4* P = pred + base;
    const float4* T = trgt + base;

    float sp = 0.f, st = 0.f, spp = 0.f, stt = 0.f, spt = 0.f;

    float4 a0, a1, at0, at1;   // batch A
    float4 b0, b1, bt0, bt1;   // batch B
    float4 g0, g1, gt0, gt1;   // batch C

#define LOADB(r0, r1, rt0, rt1, bk) do { \
    r0  = P[((bk)*2+0)*THREADS]; r1  = P[((bk)*2+1)*THREADS]; \
    rt0 = T[((bk)*2+0)*THREADS]; rt1 = T[((bk)*2+1)*THREADS]; } while (0)

#define ACC1(p, t) do { \
    sp  += (p).x + (p).y + (p).z + (p).w; \
    st  += (t).x + (t).y + (t).z + (t).w; \
    spp += (p).x*(p).x + (p).y*(p).y + (p).z*(p).z + (p).w*(p).w; \
    stt += (t).x*(t).x + (t).y*(t).y + (t).z*(t).z + (t).w*(t).w; \
    spt += (p).x*(t).x + (p).y*(t).y + (p).z*(t).z + (p).w*(t).w; } while (0)

    LOADB(a0, a1, at0, at1, 0);   //  4 in flight
    LOADB(b0, b1, bt0, bt1, 1);   //  8 in flight
    LOADB(g0, g1, gt0, gt1, 2);   // 12 in flight
    ACC1(a0, at0); ACC1(a1, at1); // consume A (waits only on A)
    LOADB(a0, a1, at0, at1, 3);   // refill A -> 12 in flight again
    ACC1(b0, bt0); ACC1(b1, bt1);
    ACC1(g0, gt0); ACC1(g1, gt1);
    ACC1(a0, at0); ACC1(a1, at1);

#undef LOADB
#undef ACC1

    // Wave-64 reduce via shfl_down (5 values)
    #pragma unroll
    for (int off = 32; off >= 1; off >>= 1) {
        sp  += __shfl_down(sp,  off);
        st  += __shfl_down(st,  off);
        spp += __shfl_down(spp, off);
        stt += __shfl_down(stt, off);
        spt += __shfl_down(spt, off);
    }

    __shared__ float red[4][5];
    const int lane = threadIdx.x & 63;
    const int wave = threadIdx.x >> 6;
    if (lane == 0) {
        red[wave][0] = sp;  red[wave][1] = st;  red[wave][2] = spp;
        red[wave][3] = stt; red[wave][4] = spt;
    }
    __syncthreads();
    if (threadIdx.x == 0) {
        // Records padded to 8 floats so finalize reads 2xfloat4 per record.
        float* dst = ws + (size_t)bid * 8;
        #pragma unroll
        for (int k = 0; k < 5; ++k)
            dst[k] = red[0][k] + red[1][k] + red[2][k] + red[3][k];
        dst[5] = 0.f; dst[6] = 0.f; dst[7] = 0.f;
    }
}

__global__ __launch_bounds__(B_ROWS)
void signal_loss_finalize(const float4* __restrict__ ws4,
                          float* __restrict__ out)
{
    const int row = threadIdx.x;  // one thread per row, 256 threads

    // Issue all 16 float4 loads up front (independent, one latency shot).
    float4 lo[SLICES], hi[SLICES];
    #pragma unroll
    for (int sl = 0; sl < SLICES; ++sl) {
        const size_t rec = ((size_t)row * SLICES + sl) * 2;  // 2 float4 per record
        lo[sl] = ws4[rec + 0];
        hi[sl] = ws4[rec + 1];
    }

    double s0=0.0, s1=0.0, s2=0.0, s3=0.0, s4=0.0;
    #pragma unroll
    for (int sl = 0; sl < SLICES; ++sl) {
        s0 += (double)lo[sl].x;  // sum p
        s1 += (double)lo[sl].y;  // sum t
        s2 += (double)lo[sl].z;  // sum p^2
        s3 += (double)lo[sl].w;  // sum t^2
        s4 += (double)hi[sl].x;  // sum p*t
    }

    const double n = (double)L_COLS;
    const double num   = s4 - s0 * s1 / n;        // sum(xm*ym)
    const double den_t = s3 - s1 * s1 / n;        // sum(xm^2), xm from y_true
    const double den_p = s2 - s0 * s0 / n;        // sum(ym^2), ym from y_pred
    double den = sqrt(den_t * den_p);
    den = den > 1e-8 ? den : 1e-8;
    double romr = 1.0 - num / den;                // 1 - r for this row
    double sd   = s2 + s3 - 2.0 * s4;             // sum((p-t)^2) for this row

    #pragma unroll
    for (int off = 32; off >= 1; off >>= 1) {
        romr += __shfl_down(romr, off);
        sd   += __shfl_down(sd,   off);
    }
    __shared__ double w0[4], w1[4];
    const int lane = threadIdx.x & 63;
    const int wave = threadIdx.x >> 6;
    if (lane == 0) { w0[wave] = romr; w1[wave] = sd; }
    __syncthreads();
    if (threadIdx.x == 0) {
        const double corr = (w0[0] + w0[1] + w0[2] + w0[3]) / (double)B_ROWS;
        const double mse  = (w1[0] + w1[1] + w1[2] + w1[3])
                          / ((double)B_ROWS * (double)L_COLS);
        out[0] = (float)(0.7 * mse + 0.3 * corr);
    }
}

extern "C" void kernel_launch(void* const* d_in, const int* in_sizes, int n_in,
                              void* d_out, int out_size, void* d_ws, size_t ws_size,
                              hipStream_t stream) {
    const float4* pred = (const float4*)d_in[0];  // y_pred
    const float4* trgt = (const float4*)d_in[1];  // y_true
    float* ws  = (float*)d_ws;                    // NBLOCKS*8 floats = 64 KiB partials
    float* out = (float*)d_out;

    signal_loss_partials<<<NBLOCKS, THREADS, 0, stream>>>(pred, trgt, ws);
    signal_loss_finalize<<<1, B_ROWS, 0, stream>>>((const float4*)ws, out);
}

// Round 6
// 28.836 us; speedup vs baseline: 1.0129x; 1.0129x over previous
//
#include <hip/hip_runtime.h>

// Problem constants (match reference)
#define B_ROWS   256
#define L_COLS   65536
#define SLICES   8
#define THREADS  256
#define NBLOCKS  (B_ROWS * SLICES)          // 2048 blocks
#define V_ROW    (L_COLS / 4)               // 16384 float4 per row
#define V_SLICE  (V_ROW / SLICES)           // 2048 float4 per slice
// Per thread: 8 float4 per input = 16 loads, ALL issued up front via inline
// asm (register-pinned, compiler cannot recycle), consumed in 4 batches via
// counted s_waitcnt vmcnt(12/8/4/0) + sched_barrier(0) (guide rule #18).
// 256 B/lane in flight. sum((p-t)^2) = spp + stt - 2*spt at finalize (f64).

#define GLOAD(dst, ptr) \
    asm volatile("global_load_dwordx4 %0, %1, off" : "=v"(dst) : "v"(ptr) : "memory")

#define WAITV(n) do { \
    asm volatile("s_waitcnt vmcnt(" #n ")" ::: "memory"); \
    __builtin_amdgcn_sched_barrier(0); } while (0)

__global__ __launch_bounds__(THREADS, 4)
void signal_loss_partials(const float4* __restrict__ pred,
                          const float4* __restrict__ trgt,
                          float* __restrict__ ws)
{
    const int bid   = blockIdx.x;
    const int row   = bid >> 3;             // / SLICES
    const int slice = bid & (SLICES - 1);
    const size_t base = (size_t)row * V_ROW + (size_t)slice * V_SLICE + threadIdx.x;
    const float4* P = pred + base;
    const float4* T = trgt + base;

    float4 a0, a1, at0, at1;   // batch A
    float4 b0, b1, bt0, bt1;   // batch B
    float4 c0, c1, ct0, ct1;   // batch C
    float4 d0, d1, dt0, dt1;   // batch D

    // Issue all 16 loads back-to-back: 16 outstanding, 256 B/lane.
    GLOAD(a0,  P + 0 * THREADS); GLOAD(a1,  P + 1 * THREADS);
    GLOAD(at0, T + 0 * THREADS); GLOAD(at1, T + 1 * THREADS);
    GLOAD(b0,  P + 2 * THREADS); GLOAD(b1,  P + 3 * THREADS);
    GLOAD(bt0, T + 2 * THREADS); GLOAD(bt1, T + 3 * THREADS);
    GLOAD(c0,  P + 4 * THREADS); GLOAD(c1,  P + 5 * THREADS);
    GLOAD(ct0, T + 4 * THREADS); GLOAD(ct1, T + 5 * THREADS);
    GLOAD(d0,  P + 6 * THREADS); GLOAD(d1,  P + 7 * THREADS);
    GLOAD(dt0, T + 6 * THREADS); GLOAD(dt1, T + 7 * THREADS);

    float sp = 0.f, st = 0.f, spp = 0.f, stt = 0.f, spt = 0.f;

#define ACC1(p, t) do { \
    sp  += (p).x + (p).y + (p).z + (p).w; \
    st  += (t).x + (t).y + (t).z + (t).w; \
    spp += (p).x*(p).x + (p).y*(p).y + (p).z*(p).z + (p).w*(p).w; \
    stt += (t).x*(t).x + (t).y*(t).y + (t).z*(t).z + (t).w*(t).w; \
    spt += (p).x*(t).x + (p).y*(t).y + (p).z*(t).z + (p).w*(t).w; } while (0)

    WAITV(12); ACC1(a0, at0); ACC1(a1, at1);
    WAITV(8);  ACC1(b0, bt0); ACC1(b1, bt1);
    WAITV(4);  ACC1(c0, ct0); ACC1(c1, ct1);
    WAITV(0);  ACC1(d0, dt0); ACC1(d1, dt1);

#undef ACC1

    // Wave-64 reduce via shfl_down (5 values)
    #pragma unroll
    for (int off = 32; off >= 1; off >>= 1) {
        sp  += __shfl_down(sp,  off);
        st  += __shfl_down(st,  off);
        spp += __shfl_down(spp, off);
        stt += __shfl_down(stt, off);
        spt += __shfl_down(spt, off);
    }

    __shared__ float red[4][5];
    const int lane = threadIdx.x & 63;
    const int wave = threadIdx.x >> 6;
    if (lane == 0) {
        red[wave][0] = sp;  red[wave][1] = st;  red[wave][2] = spp;
        red[wave][3] = stt; red[wave][4] = spt;
    }
    __syncthreads();
    if (threadIdx.x == 0) {
        // Records padded to 8 floats so finalize reads 2xfloat4 per record.
        float* dst = ws + (size_t)bid * 8;
        #pragma unroll
        for (int k = 0; k < 5; ++k)
            dst[k] = red[0][k] + red[1][k] + red[2][k] + red[3][k];
        dst[5] = 0.f; dst[6] = 0.f; dst[7] = 0.f;
    }
}

__global__ __launch_bounds__(B_ROWS)
void signal_loss_finalize(const float4* __restrict__ ws4,
                          float* __restrict__ out)
{
    const int row = threadIdx.x;  // one thread per row, 256 threads

    // Issue all 16 float4 loads up front (independent, one latency shot).
    float4 lo[SLICES], hi[SLICES];
    #pragma unroll
    for (int sl = 0; sl < SLICES; ++sl) {
        const size_t rec = ((size_t)row * SLICES + sl) * 2;  // 2 float4 per record
        lo[sl] = ws4[rec + 0];
        hi[sl] = ws4[rec + 1];
    }

    double s0=0.0, s1=0.0, s2=0.0, s3=0.0, s4=0.0;
    #pragma unroll
    for (int sl = 0; sl < SLICES; ++sl) {
        s0 += (double)lo[sl].x;  // sum p
        s1 += (double)lo[sl].y;  // sum t
        s2 += (double)lo[sl].z;  // sum p^2
        s3 += (double)lo[sl].w;  // sum t^2
        s4 += (double)hi[sl].x;  // sum p*t
    }

    const double n = (double)L_COLS;
    const double num   = s4 - s0 * s1 / n;        // sum(xm*ym)
    const double den_t = s3 - s1 * s1 / n;        // sum(xm^2), xm from y_true
    const double den_p = s2 - s0 * s0 / n;        // sum(ym^2), ym from y_pred
    double den = sqrt(den_t * den_p);
    den = den > 1e-8 ? den : 1e-8;
    double romr = 1.0 - num / den;                // 1 - r for this row
    double sd   = s2 + s3 - 2.0 * s4;             // sum((p-t)^2) for this row

    #pragma unroll
    for (int off = 32; off >= 1; off >>= 1) {
        romr += __shfl_down(romr, off);
        sd   += __shfl_down(sd,   off);
    }
    __shared__ double w0[4], w1[4];
    const int lane = threadIdx.x & 63;
    const int wave = threadIdx.x >> 6;
    if (lane == 0) { w0[wave] = romr; w1[wave] = sd; }
    __syncthreads();
    if (threadIdx.x == 0) {
        const double corr = (w0[0] + w0[1] + w0[2] + w0[3]) / (double)B_ROWS;
        const double mse  = (w1[0] + w1[1] + w1[2] + w1[3])
                          / ((double)B_ROWS * (double)L_COLS);
        out[0] = (float)(0.7 * mse + 0.3 * corr);
    }
}

extern "C" void kernel_launch(void* const* d_in, const int* in_sizes, int n_in,
                              void* d_out, int out_size, void* d_ws, size_t ws_size,
                              hipStream_t stream) {
    const float4* pred = (const float4*)d_in[0];  // y_pred
    const float4* trgt = (const float4*)d_in[1];  // y_true
    float* ws  = (float*)d_ws;                    // NBLOCKS*8 floats = 64 KiB partials
    float* out = (float*)d_out;

    signal_loss_partials<<<NBLOCKS, THREADS, 0, stream>>>(pred, trgt, ws);
    signal_loss_finalize<<<1, B_ROWS, 0, stream>>>((const float4*)ws, out);
}